// Round 1
// baseline (49.758 us; speedup 1.0000x reference)
//
#include <hip/hip_runtime.h>

// Normalizer: out[b,i,j] = adj[b,i,j] * inv_degree[b,i]
// adj: [B=4, N=3000, N=3000] float32.  One block per row, row read once.

#define N_COLS 3000
#define VEC_PER_ROW (N_COLS / 4)   // 750 float4 per row (12000 B, 16B-aligned stride)

__global__ __launch_bounds__(256)
void Normalizer_33243046871372_kernel(const float* __restrict__ adj,
                                      float* __restrict__ out) {
    const int row = blockIdx.x;
    const long long base = (long long)row * N_COLS;
    const float4* __restrict__ in4  = reinterpret_cast<const float4*>(adj + base);
    float4* __restrict__       out4 = reinterpret_cast<float4*>(out + base);

    const int tid = threadIdx.x;

    // 750 float4s over 256 threads: loads at tid, tid+256, tid+512(partial)
    float4 v0 = in4[tid];
    float4 v1 = in4[tid + 256];
    const bool has2 = (tid < VEC_PER_ROW - 512);   // tid < 238
    float4 v2 = has2 ? in4[tid + 512] : make_float4(0.f, 0.f, 0.f, 0.f);

    float s = (v0.x + v0.y) + (v0.z + v0.w)
            + (v1.x + v1.y) + (v1.z + v1.w)
            + (v2.x + v2.y) + (v2.z + v2.w);

    // wave-64 butterfly/shfl-down reduce
    #pragma unroll
    for (int off = 32; off > 0; off >>= 1)
        s += __shfl_down(s, off, 64);

    __shared__ float ws[4];
    const int lane = tid & 63;
    const int wid  = tid >> 6;
    if (lane == 0) ws[wid] = s;
    __syncthreads();

    const float deg = (ws[0] + ws[1]) + (ws[2] + ws[3]);
    const float inv = (deg == 0.0f) ? 0.0f : 1.0f / deg;

    v0.x *= inv; v0.y *= inv; v0.z *= inv; v0.w *= inv;
    v1.x *= inv; v1.y *= inv; v1.z *= inv; v1.w *= inv;

    out4[tid]       = v0;
    out4[tid + 256] = v1;
    if (has2) {
        v2.x *= inv; v2.y *= inv; v2.z *= inv; v2.w *= inv;
        out4[tid + 512] = v2;
    }
}

extern "C" void kernel_launch(void* const* d_in, const int* in_sizes, int n_in,
                              void* d_out, int out_size, void* d_ws, size_t ws_size,
                              hipStream_t stream) {
    const float* adj = (const float*)d_in[0];
    float* out = (float*)d_out;
    const int total = in_sizes[0];            // B * N * N
    const int rows = total / N_COLS;          // B * N = 12000
    Normalizer_33243046871372_kernel<<<rows, 256, 0, stream>>>(adj, out);
}

// Round 3
// 48.417 us; speedup vs baseline: 1.0277x; 1.0277x over previous
//
#include <hip/hip_runtime.h>

// Normalizer: out[b,i,j] = adj[b,i,j] * inv_degree[b,i]
// adj: [B=4, N=3000, N=3000] float32.  One block per row, row read once.
// Stores are non-temporal so the (never re-read) output doesn't evict the
// input from L3 between graph replays.

#define N_COLS 3000
#define VEC_PER_ROW (N_COLS / 4)   // 750 float4 per row (12000 B, 16B-aligned stride)

typedef float v4f __attribute__((ext_vector_type(4)));  // builtin vector: nt-store-compatible

__global__ __launch_bounds__(256)
void Normalizer_33243046871372_kernel(const float* __restrict__ adj,
                                      float* __restrict__ out) {
    const int row = blockIdx.x;
    const long long base = (long long)row * N_COLS;
    const v4f* __restrict__ in4  = reinterpret_cast<const v4f*>(adj + base);
    v4f* __restrict__       out4 = reinterpret_cast<v4f*>(out + base);

    const int tid = threadIdx.x;

    // 750 float4s over 256 threads: loads at tid, tid+256, tid+512(partial)
    v4f v0 = in4[tid];
    v4f v1 = in4[tid + 256];
    const bool has2 = (tid < VEC_PER_ROW - 512);   // tid < 238
    v4f v2 = has2 ? in4[tid + 512] : (v4f){0.f, 0.f, 0.f, 0.f};

    float s = (v0.x + v0.y) + (v0.z + v0.w)
            + (v1.x + v1.y) + (v1.z + v1.w)
            + (v2.x + v2.y) + (v2.z + v2.w);

    // wave-64 shfl-down reduce
    #pragma unroll
    for (int off = 32; off > 0; off >>= 1)
        s += __shfl_down(s, off, 64);

    __shared__ float ws[4];
    const int lane = tid & 63;
    const int wid  = tid >> 6;
    if (lane == 0) ws[wid] = s;
    __syncthreads();

    const float deg = (ws[0] + ws[1]) + (ws[2] + ws[3]);
    const float inv = (deg == 0.0f) ? 0.0f : 1.0f / deg;

    v0 *= inv;
    v1 *= inv;

    __builtin_nontemporal_store(v0, &out4[tid]);
    __builtin_nontemporal_store(v1, &out4[tid + 256]);
    if (has2) {
        v2 *= inv;
        __builtin_nontemporal_store(v2, &out4[tid + 512]);
    }
}

extern "C" void kernel_launch(void* const* d_in, const int* in_sizes, int n_in,
                              void* d_out, int out_size, void* d_ws, size_t ws_size,
                              hipStream_t stream) {
    const float* adj = (const float*)d_in[0];
    float* out = (float*)d_out;
    const int total = in_sizes[0];            // B * N * N
    const int rows = total / N_COLS;          // B * N = 12000
    Normalizer_33243046871372_kernel<<<rows, 256, 0, stream>>>(adj, out);
}